// Round 1
// baseline (11.036 us; speedup 1.0000x reference)
//
#include <hip/hip_runtime.h>

// The reference network is input-independent: conv1 has kernel width 1,
// stride 2, padding 1 on a width-1 input, so both output columns sample
// only zero-padding and conv1's output is leaky(b1) broadcast. Everything
// downstream is a closed-form function of the weights only. We evaluate
// the 90 expert scalars once and broadcast to the [2048, 90] output.

#define SLOPE 0.33f

__device__ __forceinline__ float leaky(float v) {
    return v >= 0.0f ? v : SLOPE * v;
}

// One block = one wave (64 lanes) per expert.
__global__ void __launch_bounds__(64) expert_eval(
    const float* __restrict__ b1,   // [90,16]
    const float* __restrict__ W2,   // [90,32,16,3]
    const float* __restrict__ b2,   // [90,32]
    const float* __restrict__ W3,   // [90,64,32,3]
    const float* __restrict__ b3,   // [90,64]
    const float* __restrict__ Wfc,  // [90,64]
    const float* __restrict__ bfc,  // [90]
    float* __restrict__ vals)       // [90] scratch
{
    const int e = blockIdx.x;
    const int t = threadIdx.x;

    __shared__ float a1s[16];
    __shared__ float t2s[32], m2s[32], u2s[32];

    // Stage 1: conv1 output is leaky(b1[c]) everywhere (patch is all pad).
    if (t < 16) a1s[t] = leaky(b1[e * 16 + t]);
    __syncthreads();

    // Stage 2: w-col 1 of conv2 output has 3 distinct row values
    // (top: taps 1,2; mid x21: taps 0,1,2; bottom: taps 0,1).
    if (t < 32) {
        const float* w2 = W2 + (size_t)(e * 32 + t) * 16 * 3;
        float stop = 0.f, smid = 0.f, sbot = 0.f;
        #pragma unroll
        for (int c = 0; c < 16; ++c) {
            float w0 = w2[c * 3 + 0];
            float w1 = w2[c * 3 + 1];
            float w2v = w2[c * 3 + 2];
            float a = a1s[c];
            stop += a * (w1 + w2v);
            smid += a * (w0 + w1 + w2v);
            sbot += a * (w0 + w1);
        }
        float b = b2[e * 32 + t];
        t2s[t] = leaky(b + stop);   // h2 = 0
        m2s[t] = leaky(b + smid);   // h2 = 1..21 (21 rows)
        u2s[t] = leaky(b + sbot);   // h2 = 22
    }
    __syncthreads();

    // Stage 3 (+ pool + fc partial): lane g handles output channel g.
    // w-col 0 of conv3 out = leaky(b3) (12 rows); w-col 1:
    //   h3=0:      W3[.,c,1]*t2 + W3[.,c,2]*m2
    //   h3=1..10:  (W3 taps sum)*m2   (10 rows)
    //   h3=11:     W3[.,c,0]*m2 + W3[.,c,1]*u2
    const float* w3 = W3 + (size_t)(e * 64 + t) * 32 * 3;
    float stop = 0.f, smid = 0.f, sbot = 0.f;
    #pragma unroll
    for (int c = 0; c < 32; ++c) {
        float w0 = w3[c * 3 + 0];
        float w1 = w3[c * 3 + 1];
        float w2v = w3[c * 3 + 2];
        float m = m2s[c];
        stop += w1 * t2s[c] + w2v * m;
        smid += (w0 + w1 + w2v) * m;
        sbot += w0 * m + w1 * u2s[c];
    }
    float b = b3[e * 64 + t];
    float pooled = (12.0f * leaky(b)
                    + leaky(b + stop)
                    + 10.0f * leaky(b + smid)
                    + leaky(b + sbot)) * (1.0f / 24.0f);

    float contrib = Wfc[e * 64 + t] * pooled;
    #pragma unroll
    for (int off = 32; off > 0; off >>= 1)
        contrib += __shfl_down(contrib, off, 64);
    if (t == 0)
        vals[e] = leaky(contrib + bfc[e]);
}

// Coalesced broadcast: out[b*90 + e] = vals[e].
__global__ void __launch_bounds__(256) broadcast_out(
    const float* __restrict__ vals,
    float* __restrict__ out, int total)
{
    __shared__ float v[90];
    if (threadIdx.x < 90) v[threadIdx.x] = vals[threadIdx.x];
    __syncthreads();
    int i = blockIdx.x * blockDim.x + threadIdx.x;
    if (i < total) out[i] = v[i % 90];
}

extern "C" void kernel_launch(void* const* d_in, const int* in_sizes, int n_in,
                              void* d_out, int out_size, void* d_ws, size_t ws_size,
                              hipStream_t stream) {
    // setup_inputs order: x, W1, b1, W2, b2, W3, b3, Wfc, bfc
    // x (d_in[0]) and W1 (d_in[1]) are provably unused (conv1 sees only padding).
    const float* b1  = (const float*)d_in[2];
    const float* W2  = (const float*)d_in[3];
    const float* b2  = (const float*)d_in[4];
    const float* W3  = (const float*)d_in[5];
    const float* b3  = (const float*)d_in[6];
    const float* Wfc = (const float*)d_in[7];
    const float* bfc = (const float*)d_in[8];

    float* out  = (float*)d_out;
    float* vals = (float*)d_ws;  // 90 floats

    expert_eval<<<90, 64, 0, stream>>>(b1, W2, b2, W3, b3, Wfc, bfc, vals);

    const int total = out_size;  // 2048 * 90
    const int block = 256;
    const int grid = (total + block - 1) / block;
    broadcast_out<<<grid, block, 0, stream>>>(vals, out, total);
}

// Round 2
// 10.217 us; speedup vs baseline: 1.0801x; 1.0801x over previous
//
#include <hip/hip_runtime.h>

// The reference network is input-independent: conv1 has kernel width 1,
// stride 2, padding 1 on a width-1 input, so both output columns sample
// only zero-padding and conv1's output is leaky(b1) broadcast. Everything
// downstream is a closed-form function of the weights only.
//
// Single fused kernel (launch-overhead-bound problem): 90 experts x 8 row
// chunks = 720 one-wave blocks. Each block redundantly evaluates its
// expert's scalar (~130 VALU insts, bit-identical across chunks) and
// writes its 256-row slice of that expert's output column.

#define SLOPE 0.33f
#define NCHUNK 8
#define BATCH 2048

__device__ __forceinline__ float leaky(float v) {
    return v >= 0.0f ? v : SLOPE * v;
}

__global__ void __launch_bounds__(64) fused_expert_broadcast(
    const float* __restrict__ b1,   // [90,16]
    const float* __restrict__ W2,   // [90,32,16,3]
    const float* __restrict__ b2,   // [90,32]
    const float* __restrict__ W3,   // [90,64,32,3]
    const float* __restrict__ b3,   // [90,64]
    const float* __restrict__ Wfc,  // [90,64]
    const float* __restrict__ bfc,  // [90]
    float* __restrict__ out)        // [2048,90]
{
    const int e     = blockIdx.x / NCHUNK;
    const int chunk = blockIdx.x % NCHUNK;
    const int t = threadIdx.x;

    __shared__ float a1s[16];
    __shared__ float t2s[32], m2s[32], u2s[32];

    // Stage 1: conv1 output is leaky(b1[c]) everywhere (patch is all pad).
    if (t < 16) a1s[t] = leaky(b1[e * 16 + t]);
    __syncthreads();

    // Stage 2: w-col 1 of conv2 output has 3 distinct row values
    // (top: taps 1,2; mid x21: taps 0,1,2; bottom: taps 0,1).
    if (t < 32) {
        const float* w2 = W2 + (size_t)(e * 32 + t) * 16 * 3;
        float stop = 0.f, smid = 0.f, sbot = 0.f;
        #pragma unroll
        for (int c = 0; c < 16; ++c) {
            float w0 = w2[c * 3 + 0];
            float w1 = w2[c * 3 + 1];
            float w2v = w2[c * 3 + 2];
            float a = a1s[c];
            stop += a * (w1 + w2v);
            smid += a * (w0 + w1 + w2v);
            sbot += a * (w0 + w1);
        }
        float b = b2[e * 32 + t];
        t2s[t] = leaky(b + stop);   // h2 = 0
        m2s[t] = leaky(b + smid);   // h2 = 1..21 (21 rows)
        u2s[t] = leaky(b + sbot);   // h2 = 22
    }
    __syncthreads();

    // Stage 3 (+ pool + fc partial): lane g handles output channel g.
    //   w-col 0 of conv3 out = leaky(b3) (12 rows); w-col 1:
    //   h3=0:      W3[.,c,1]*t2 + W3[.,c,2]*m2
    //   h3=1..10:  (taps sum)*m2   (10 rows)
    //   h3=11:     W3[.,c,0]*m2 + W3[.,c,1]*u2
    const float* w3 = W3 + (size_t)(e * 64 + t) * 32 * 3;
    float stop = 0.f, smid = 0.f, sbot = 0.f;
    #pragma unroll
    for (int c = 0; c < 32; ++c) {
        float w0 = w3[c * 3 + 0];
        float w1 = w3[c * 3 + 1];
        float w2v = w3[c * 3 + 2];
        float m = m2s[c];
        stop += w1 * t2s[c] + w2v * m;
        smid += (w0 + w1 + w2v) * m;
        sbot += w0 * m + w1 * u2s[c];
    }
    float b = b3[e * 64 + t];
    float pooled = (12.0f * leaky(b)
                    + leaky(b + stop)
                    + 10.0f * leaky(b + smid)
                    + leaky(b + sbot)) * (1.0f / 24.0f);

    // fc: butterfly reduce so ALL lanes hold the dot product.
    float sum = Wfc[e * 64 + t] * pooled;
    #pragma unroll
    for (int off = 32; off > 0; off >>= 1)
        sum += __shfl_xor(sum, off, 64);
    const float val = leaky(sum + bfc[e]);

    // Write this chunk's 256 rows of column e (4 dword stores per lane).
    const int rows_per_chunk = BATCH / NCHUNK;  // 256
    const int r0 = chunk * rows_per_chunk;
    #pragma unroll
    for (int i = 0; i < rows_per_chunk / 64; ++i) {
        int r = r0 + i * 64 + t;
        out[(size_t)r * 90 + e] = val;
    }
}

extern "C" void kernel_launch(void* const* d_in, const int* in_sizes, int n_in,
                              void* d_out, int out_size, void* d_ws, size_t ws_size,
                              hipStream_t stream) {
    // setup_inputs order: x, W1, b1, W2, b2, W3, b3, Wfc, bfc
    // x (d_in[0]) and W1 (d_in[1]) are provably unused (conv1 sees only padding).
    const float* b1  = (const float*)d_in[2];
    const float* W2  = (const float*)d_in[3];
    const float* b2  = (const float*)d_in[4];
    const float* W3  = (const float*)d_in[5];
    const float* b3  = (const float*)d_in[6];
    const float* Wfc = (const float*)d_in[7];
    const float* bfc = (const float*)d_in[8];

    float* out = (float*)d_out;

    fused_expert_broadcast<<<90 * NCHUNK, 64, 0, stream>>>(
        b1, W2, b2, W3, b3, Wfc, bfc, out);
}